// Round 4
// baseline (667.066 us; speedup 1.0000x reference)
//
#include <hip/hip_runtime.h>

#define N_ITEMS 500000
#define EMBED 64
#define BATCH 1024
#define JG 256                        // chunk-groups; grid = 4 M-blocks x JG
#define NCH64 ((N_ITEMS + 63) / 64)   // 7813 chunks of 64 items
#define CAP 64
#define MARGIN 0.75f                  // ~29 sigma of the 1-term bf16 dot error

typedef __attribute__((ext_vector_type(8))) __bf16 bf16x8;
typedef __attribute__((ext_vector_type(4))) float f32x4;

__device__ unsigned g_cand[BATCH * CAP];   // candidate j lists (written before read)

__device__ __forceinline__ void cvt_hi(const f32x4 r0, const f32x4 r1, bf16x8& H) {
#pragma unroll
  for (int k = 0; k < 4; ++k) { H[k] = (__bf16)r0[k]; H[4 + k] = (__bf16)r1[k]; }
}

// A fragments (hi bf16 only) for this wave's 64 query rows; identical in both
// scan kernels so the approximate scores are bitwise-reproducible.
__device__ __forceinline__ void load_afrags(const float* __restrict__ emb,
                                            const int* __restrict__ idx,
                                            int m0, int l15, int kq,
                                            bf16x8 ah[4][2]) {
#pragma unroll
  for (int am = 0; am < 4; ++am) {
    int row = idx[m0 + am * 16 + l15] - 1;
    if (row < 0) row += N_ITEMS;          // numpy negative-index wrap
    const float* src = emb + (size_t)row * EMBED + kq * 8;
    cvt_hi(*(const f32x4*)(src),      *(const f32x4*)(src + 4),  ah[am][0]);
    cvt_hi(*(const f32x4*)(src + 32), *(const f32x4*)(src + 36), ah[am][1]);
  }
}

// ---- pass A: per-row max of hi*hi approx scores (self & tail excluded) ----
__global__ __launch_bounds__(256, 4)
void scan_max_kernel(const float* __restrict__ emb, const int* __restrict__ idx,
                     unsigned* __restrict__ best_u) {
  const int tid = threadIdx.x, lane = tid & 63, wv = tid >> 6;
  const int l15 = lane & 15, kq = lane >> 4;
  const int mb = blockIdx.x & 3, jg = blockIdx.x >> 2;
  const int m0 = mb * 256 + wv * 64;

  bf16x8 ah[4][2];
  load_afrags(emb, idx, m0, l15, kq, ah);

  int self_[16];
#pragma unroll
  for (int am = 0; am < 4; ++am)
#pragma unroll
    for (int r = 0; r < 4; ++r) {
      int row = idx[m0 + am * 16 + kq * 4 + r] - 1;
      if (row < 0) row += N_ITEMS;
      self_[am * 4 + r] = row;
    }

  float bs[16];
#pragma unroll
  for (int sl = 0; sl < 16; ++sl) bs[sl] = -3.4e38f;

  const float* colbase = emb + kq * 8;

  for (int c = jg; c < NCH64; c += JG) {
    bool mflag = (c == NCH64 - 1);
#pragma unroll
    for (int sl = 0; sl < 16; ++sl) mflag |= ((self_[sl] >> 6) == c);
    const bool masked = __any(mflag);

#pragma unroll
    for (int bn = 0; bn < 4; ++bn) {
      int jr = c * 64 + bn * 16 + l15;
      if (jr >= N_ITEMS) jr = N_ITEMS - 1;
      const float* src = colbase + (size_t)jr * EMBED;
      bf16x8 bh0, bh1;
      cvt_hi(*(const f32x4*)(src),      *(const f32x4*)(src + 4),  bh0);
      cvt_hi(*(const f32x4*)(src + 32), *(const f32x4*)(src + 36), bh1);

      const f32x4 zero = {0.f, 0.f, 0.f, 0.f};
      f32x4 acc[4];
#pragma unroll
      for (int am = 0; am < 4; ++am) {
        acc[am] = __builtin_amdgcn_mfma_f32_16x16x32_bf16(ah[am][0], bh0, zero, 0, 0, 0);
        acc[am] = __builtin_amdgcn_mfma_f32_16x16x32_bf16(ah[am][1], bh1, acc[am], 0, 0, 0);
      }
      const int jc = c * 64 + bn * 16 + l15;
      if (!masked) {   // hot path: one v_max per score
#pragma unroll
        for (int am = 0; am < 4; ++am)
#pragma unroll
          for (int r = 0; r < 4; ++r)
            bs[am * 4 + r] = fmaxf(bs[am * 4 + r], acc[am][r]);
      } else {         // rare: chunk contains a self index or the ragged tail
#pragma unroll
        for (int am = 0; am < 4; ++am)
#pragma unroll
          for (int r = 0; r < 4; ++r) {
            const int sl = am * 4 + r;
            float v = (jc < N_ITEMS && jc != self_[sl]) ? acc[am][r] : -3.4e38f;
            bs[sl] = fmaxf(bs[sl], v);
          }
      }
    }
  }

  // reduce over the 16 lanes of this kq-group (xor 1,2,4,8 stays in-group)
#pragma unroll
  for (int off = 1; off < 16; off <<= 1)
#pragma unroll
    for (int sl = 0; sl < 16; ++sl)
      bs[sl] = fmaxf(bs[sl], __shfl_xor(bs[sl], off, 64));

  if (l15 == 0) {
#pragma unroll
    for (int sl = 0; sl < 16; ++sl) {
      union { float f; int i; unsigned u; } cv; cv.f = bs[sl];
      unsigned mu = (cv.i < 0) ? ~cv.u : (cv.u | 0x80000000u);
      atomicMax(best_u + m0 + (sl >> 2) * 16 + kq * 4 + (sl & 3), mu);
    }
  }
}

// ---- pass B: re-scan, push every j with approx >= rowmax - MARGIN ----
__global__ __launch_bounds__(256, 4)
void collect_kernel(const float* __restrict__ emb, const int* __restrict__ idx,
                    const unsigned* __restrict__ best_u, unsigned* __restrict__ cnt) {
  const int tid = threadIdx.x, lane = tid & 63, wv = tid >> 6;
  const int l15 = lane & 15, kq = lane >> 4;
  const int mb = blockIdx.x & 3, jg = blockIdx.x >> 2;
  const int m0 = mb * 256 + wv * 64;

  bf16x8 ah[4][2];
  load_afrags(emb, idx, m0, l15, kq, ah);

  float th[16];
#pragma unroll
  for (int am = 0; am < 4; ++am)
#pragma unroll
    for (int r = 0; r < 4; ++r) {
      unsigned tu = best_u[m0 + am * 16 + kq * 4 + r];
      union { unsigned u; float f; } cv;
      cv.u = (tu & 0x80000000u) ? (tu & 0x7FFFFFFFu) : ~tu;
      th[am * 4 + r] = cv.f - MARGIN;
    }

  const float* colbase = emb + kq * 8;

  for (int c = jg; c < NCH64; c += JG) {
#pragma unroll
    for (int bn = 0; bn < 4; ++bn) {
      int jr = c * 64 + bn * 16 + l15;
      if (jr >= N_ITEMS) jr = N_ITEMS - 1;
      const float* src = colbase + (size_t)jr * EMBED;
      bf16x8 bh0, bh1;
      cvt_hi(*(const f32x4*)(src),      *(const f32x4*)(src + 4),  bh0);
      cvt_hi(*(const f32x4*)(src + 32), *(const f32x4*)(src + 36), bh1);

      const f32x4 zero = {0.f, 0.f, 0.f, 0.f};
      f32x4 acc[4];
#pragma unroll
      for (int am = 0; am < 4; ++am) {
        acc[am] = __builtin_amdgcn_mfma_f32_16x16x32_bf16(ah[am][0], bh0, zero, 0, 0, 0);
        acc[am] = __builtin_amdgcn_mfma_f32_16x16x32_bf16(ah[am][1], bh1, acc[am], 0, 0, 0);
      }

      bool hit = false;
#pragma unroll
      for (int am = 0; am < 4; ++am)
#pragma unroll
        for (int r = 0; r < 4; ++r) hit |= (acc[am][r] >= th[am * 4 + r]);

      if (__any(hit)) {   // rare: ~2 pushes per row over the whole grid
        const int jc = c * 64 + bn * 16 + l15;
#pragma unroll
        for (int am = 0; am < 4; ++am)
#pragma unroll
          for (int r = 0; r < 4; ++r) {
            const int sl = am * 4 + r;
            if (acc[am][r] >= th[sl] && jc < N_ITEMS) {
              const int row = m0 + am * 16 + kq * 4 + r;
              unsigned pos = atomicAdd(cnt + row, 1u);
              if (pos < CAP) g_cand[row * CAP + pos] = (unsigned)jc;
            }
          }
      }
    }
  }
}

// ---- pass C: exact fp32 rescore of candidates, write final outputs ----
__global__ void rescore_kernel(const float* __restrict__ emb, const int* __restrict__ idx,
                               const unsigned* __restrict__ cnt,
                               const float* __restrict__ mn, const float* __restrict__ mx,
                               float* __restrict__ out) {
  int r = blockIdx.x * blockDim.x + threadIdx.x;
  if (r >= BATCH) return;
  int self = idx[r] - 1;
  if (self < 0) self += N_ITEMS;
  const float* a = emb + (size_t)self * EMBED;
  float av[EMBED];
#pragma unroll
  for (int k = 0; k < EMBED; ++k) av[k] = a[k];

  unsigned n = cnt[r];
  if (n > CAP) n = CAP;
  float bestv = -3.4e38f;
  unsigned bj = 0xFFFFFFFFu;
  for (unsigned i = 0; i < n; ++i) {
    unsigned j = g_cand[r * CAP + i];
    if ((int)j == self) continue;
    const float* b = emb + (size_t)j * EMBED;
    float d = 0.f;
#pragma unroll
    for (int k = 0; k < EMBED; ++k) d = fmaf(av[k], b[k], d);
    if (d > bestv || (d == bestv && j < bj)) { bestv = d; bj = j; }
  }
  float lo = mn[0], hi = mx[0];
  out[r] = (float)(bj + 1);                  // indices = argmax + 1
  out[BATCH + r] = (bestv - lo) / (hi - lo); // normalized score
}

extern "C" void kernel_launch(void* const* d_in, const int* in_sizes, int n_in,
                              void* d_out, int out_size, void* d_ws, size_t ws_size,
                              hipStream_t stream) {
  const float* emb = (const float*)d_in[0];
  const int* idx   = (const int*)d_in[1];
  const float* mn  = (const float*)d_in[2];
  const float* mx  = (const float*)d_in[3];
  unsigned* best_u = (unsigned*)d_ws;        // [BATCH]
  unsigned* cnt    = best_u + BATCH;         // [BATCH]

  hipMemsetAsync(d_ws, 0, 2 * BATCH * sizeof(unsigned), stream);

  scan_max_kernel<<<dim3(4 * JG), dim3(256), 0, stream>>>(emb, idx, best_u);
  collect_kernel<<<dim3(4 * JG), dim3(256), 0, stream>>>(emb, idx, best_u, cnt);
  rescore_kernel<<<dim3(4), dim3(256), 0, stream>>>(emb, idx, cnt, mn, mx,
                                                    (float*)d_out);
}

// Round 5
// 361.344 us; speedup vs baseline: 1.8461x; 1.8461x over previous
//
#include <hip/hip_runtime.h>

#define N_ITEMS 500000
#define EMBED 64
#define BATCH 1024
#define NB 256                        // scan blocks (1/CU); block b owns chunks b, b+NB, ...
#define NCH64 ((N_ITEMS + 63) / 64)   // 7813 chunks of 64 items
#define CAP 64
#define MARGIN 0.75f                  // >> 2x max approx error (~0.38)

typedef __attribute__((ext_vector_type(8))) __bf16 bf16x8;
typedef __attribute__((ext_vector_type(4))) float f32x4;

__device__ unsigned g_cand[BATCH * CAP];

__device__ __forceinline__ void cvt_hi(const f32x4 r0, const f32x4 r1, bf16x8& H) {
#pragma unroll
  for (int k = 0; k < 4; ++k) { H[k] = (__bf16)r0[k]; H[4 + k] = (__bf16)r1[k]; }
}

// Shared scan skeleton: 512 threads, 8 waves x 128 query rows; B chunk (64 items
// x 64 k) staged fp32->bf16 into swizzled LDS, double-buffered, prefetch issued
// a full compute phase ahead. Both passes use this identical math -> bitwise-
// identical approximate scores.
#define SCAN_PROLOGUE()                                                        \
  const int tid = threadIdx.x, lane = tid & 63, wv = tid >> 6;                 \
  const int l15 = lane & 15, kq = lane >> 4;                                   \
  const int b = blockIdx.x;                                                    \
  const int m0 = wv * 128;                                                     \
  __shared__ unsigned short Bb[2][64 * 64];                                    \
  __shared__ int sidx[BATCH];                                                  \
  for (int q = tid; q < BATCH; q += 512) {                                     \
    int row = idx[q] - 1;                                                      \
    if (row < 0) row += N_ITEMS;      /* numpy negative-index wrap */          \
    sidx[q] = row;                                                             \
  }                                                                            \
  const int sr = tid >> 3, sg = tid & 7;                                       \
  const int soff = sr * 64 + ((sg ^ (sr & 7)) << 3);                           \
  f32x4 raw0, raw1;                                                            \
  { /* prologue: load chunk b (coalesced: 32 contiguous B per thread) */       \
    int jr = b * 64 + sr;                                                      \
    if (jr >= N_ITEMS) jr = N_ITEMS - 1;                                       \
    const float* s = emb + (size_t)jr * EMBED + sg * 8;                        \
    raw0 = *(const f32x4*)s; raw1 = *(const f32x4*)(s + 4);                    \
  }                                                                            \
  __syncthreads();                                                             \
  bf16x8 ah[8][2];                                                             \
  _Pragma("unroll")                                                            \
  for (int am = 0; am < 8; ++am) {                                             \
    int row = sidx[m0 + am * 16 + l15];                                        \
    const float* src = emb + (size_t)row * EMBED + kq * 8;                     \
    cvt_hi(*(const f32x4*)(src),      *(const f32x4*)(src + 4),  ah[am][0]);   \
    cvt_hi(*(const f32x4*)(src + 32), *(const f32x4*)(src + 36), ah[am][1]);   \
  }

#define STAGE_AND_SYNC(p, c)                                                   \
  { bf16x8 H; cvt_hi(raw0, raw1, H);                                           \
    *(bf16x8*)(Bb[p] + soff) = H; }                                            \
  { int nc = (c) + NB;                                                         \
    if (nc < NCH64) {                                                          \
      int jr = nc * 64 + sr;                                                   \
      if (jr >= N_ITEMS) jr = N_ITEMS - 1;                                     \
      const float* s = emb + (size_t)jr * EMBED + sg * 8;                      \
      raw0 = *(const f32x4*)s; raw1 = *(const f32x4*)(s + 4);                  \
    } }                                                                        \
  __syncthreads();

#define COMPUTE_ACCS(p, bn)                                                    \
  const int fro = (bn * 16 + l15) * 64;                                        \
  bf16x8 bh0 = *(const bf16x8*)(Bb[p] + fro + ((kq ^ (l15 & 7)) << 3));        \
  bf16x8 bh1 = *(const bf16x8*)(Bb[p] + fro + (((4 | kq) ^ (l15 & 7)) << 3));  \
  const f32x4 zero = {0.f, 0.f, 0.f, 0.f};                                     \
  f32x4 acc[8];                                                                \
  _Pragma("unroll")                                                            \
  for (int am = 0; am < 8; ++am) {                                             \
    acc[am] = __builtin_amdgcn_mfma_f32_16x16x32_bf16(ah[am][0], bh0, zero, 0, 0, 0); \
    acc[am] = __builtin_amdgcn_mfma_f32_16x16x32_bf16(ah[am][1], bh1, acc[am], 0, 0, 0); \
  }

// ---- pass A: per-row max of approx scores (self & tail excluded) ----
__global__ __launch_bounds__(512, 2)
void scan_max_kernel(const float* __restrict__ emb, const int* __restrict__ idx,
                     unsigned* __restrict__ best_u) {
  SCAN_PROLOGUE();

  const int sa = sidx[m0 + 2 * lane], sb = sidx[m0 + 2 * lane + 1];
  float bs[32];
#pragma unroll
  for (int sl = 0; sl < 32; ++sl) bs[sl] = -3.4e38f;

  int p = 0;
  for (int c = b; c < NCH64; c += NB) {
    STAGE_AND_SYNC(p, c);
    const bool masked =
        __any((c == NCH64 - 1) | ((sa >> 6) == c) | ((sb >> 6) == c));
#pragma unroll
    for (int bn = 0; bn < 4; ++bn) {
      COMPUTE_ACCS(p, bn);
      if (!masked) {
#pragma unroll
        for (int am = 0; am < 8; ++am)
#pragma unroll
          for (int r = 0; r < 4; ++r)
            bs[am * 4 + r] = fmaxf(bs[am * 4 + r], acc[am][r]);
      } else {   // rare: self row or ragged tail in this chunk
        const int jc = c * 64 + bn * 16 + l15;
#pragma unroll
        for (int am = 0; am < 8; ++am)
#pragma unroll
          for (int r = 0; r < 4; ++r) {
            const int self = sidx[m0 + am * 16 + kq * 4 + r];
            float v = (jc < N_ITEMS && jc != self) ? acc[am][r] : -3.4e38f;
            bs[am * 4 + r] = fmaxf(bs[am * 4 + r], v);
          }
      }
    }
    p ^= 1;
  }

  // reduce over the 16 lanes of each kq group (xor 1,2,4,8 stays in-group)
#pragma unroll
  for (int off = 1; off < 16; off <<= 1)
#pragma unroll
    for (int sl = 0; sl < 32; ++sl)
      bs[sl] = fmaxf(bs[sl], __shfl_xor(bs[sl], off, 64));

  if (l15 == 0) {
#pragma unroll
    for (int sl = 0; sl < 32; ++sl) {
      union { float f; int i; unsigned u; } cv; cv.f = bs[sl];
      unsigned mu = (cv.i < 0) ? ~cv.u : (cv.u | 0x80000000u);
      atomicMax(best_u + m0 + (sl >> 2) * 16 + kq * 4 + (sl & 3), mu);
    }
  }
}

// ---- pass B: re-scan, push every j with approx >= rowmax - MARGIN ----
__global__ __launch_bounds__(512, 2)
void collect_kernel(const float* __restrict__ emb, const int* __restrict__ idx,
                    const unsigned* __restrict__ best_u, unsigned* __restrict__ cnt) {
  SCAN_PROLOGUE();

  float th[32];
#pragma unroll
  for (int am = 0; am < 8; ++am)
#pragma unroll
    for (int r = 0; r < 4; ++r) {
      unsigned tu = best_u[m0 + am * 16 + kq * 4 + r];
      union { unsigned u; float f; } cv;
      cv.u = (tu & 0x80000000u) ? (tu & 0x7FFFFFFFu) : ~tu;
      th[am * 4 + r] = cv.f - MARGIN;
    }

  int p = 0;
  for (int c = b; c < NCH64; c += NB) {
    STAGE_AND_SYNC(p, c);
#pragma unroll
    for (int bn = 0; bn < 4; ++bn) {
      COMPUTE_ACCS(p, bn);
      bool hit = false;
#pragma unroll
      for (int am = 0; am < 8; ++am)
#pragma unroll
        for (int r = 0; r < 4; ++r) hit |= (acc[am][r] >= th[am * 4 + r]);
      if (__any(hit)) {   // rare: ~2 survivors per row over the whole scan
        const int jc = c * 64 + bn * 16 + l15;
#pragma unroll
        for (int am = 0; am < 8; ++am)
#pragma unroll
          for (int r = 0; r < 4; ++r) {
            const int sl = am * 4 + r;
            if (acc[am][r] >= th[sl] && jc < N_ITEMS) {
              const int row = m0 + am * 16 + kq * 4 + r;
              unsigned pos = atomicAdd(cnt + row, 1u);
              if (pos < CAP) g_cand[row * CAP + pos] = (unsigned)jc;
            }
          }
      }
    }
    p ^= 1;
  }
}

// ---- pass C: exact fp32 rescore of candidates, write final outputs ----
__global__ void rescore_kernel(const float* __restrict__ emb, const int* __restrict__ idx,
                               const unsigned* __restrict__ cnt,
                               const float* __restrict__ mn, const float* __restrict__ mx,
                               float* __restrict__ out) {
  int r = blockIdx.x * blockDim.x + threadIdx.x;
  if (r >= BATCH) return;
  int self = idx[r] - 1;
  if (self < 0) self += N_ITEMS;
  const float* a = emb + (size_t)self * EMBED;
  float av[EMBED];
#pragma unroll
  for (int k = 0; k < EMBED; ++k) av[k] = a[k];

  unsigned n = cnt[r];
  if (n > CAP) n = CAP;
  float bestv = -3.4e38f;
  unsigned bj = 0xFFFFFFFFu;
  for (unsigned i = 0; i < n; ++i) {
    unsigned j = g_cand[r * CAP + i];
    if ((int)j == self) continue;
    const float* bv = emb + (size_t)j * EMBED;
    float d = 0.f;
#pragma unroll
    for (int k = 0; k < EMBED; ++k) d = fmaf(av[k], bv[k], d);
    if (d > bestv || (d == bestv && j < bj)) { bestv = d; bj = j; }
  }
  float lo = mn[0], hi = mx[0];
  out[r] = (float)(bj + 1);                  // indices = argmax + 1
  out[BATCH + r] = (bestv - lo) / (hi - lo); // normalized score
}

extern "C" void kernel_launch(void* const* d_in, const int* in_sizes, int n_in,
                              void* d_out, int out_size, void* d_ws, size_t ws_size,
                              hipStream_t stream) {
  const float* emb = (const float*)d_in[0];
  const int* idx   = (const int*)d_in[1];
  const float* mn  = (const float*)d_in[2];
  const float* mx  = (const float*)d_in[3];
  unsigned* best_u = (unsigned*)d_ws;        // [BATCH]
  unsigned* cnt    = best_u + BATCH;         // [BATCH]

  hipMemsetAsync(d_ws, 0, 2 * BATCH * sizeof(unsigned), stream);

  scan_max_kernel<<<dim3(NB), dim3(512), 0, stream>>>(emb, idx, best_u);
  collect_kernel<<<dim3(NB), dim3(512), 0, stream>>>(emb, idx, best_u, cnt);
  rescore_kernel<<<dim3(4), dim3(256), 0, stream>>>(emb, idx, cnt, mn, mx,
                                                    (float*)d_out);
}

// Round 6
// 329.570 us; speedup vs baseline: 2.0241x; 1.0964x over previous
//
#include <hip/hip_runtime.h>

#define N_ITEMS 500000
#define EMBED 64
#define BATCH 1024
#define NCH ((N_ITEMS + 127) / 128)   // 3907 chunks of 128 items
#define SEED_CH 128                   // seed covers items 0..16383
#define CAP 1024
#define MARGIN 0.75f                  // >> 2x max 1-term bf16 approx error (~0.35)

typedef __attribute__((ext_vector_type(8))) __bf16 bf16x8;
typedef __attribute__((ext_vector_type(4))) float f32x4;

__device__ unsigned g_cand[BATCH * CAP];   // 4 MB; valid range set by cnt each call

__device__ __forceinline__ void cvt_hi(const f32x4 r0, const f32x4 r1, bf16x8& H) {
#pragma unroll
  for (int k = 0; k < 4; ++k) { H[k] = (__bf16)r0[k]; H[4 + k] = (__bf16)r1[k]; }
}

// One scan skeleton, two modes.
// MODE 0 (seed): per-row max over the chunk range -> atomicMax(best_u).
// MODE 1 (main): bs seeded from best_u; push every j with score >= bs-MARGIN.
// Block: 512 thr = 8 waves x 64 query rows = 512 rows (blockIdx.y picks half).
// B chunk: 128 items x 64 k staged fp32->bf16 in swizzled LDS, double-buffered;
// prefetch for chunk c+stride is issued right AFTER the barrier publishing c,
// so it has the whole compute phase to complete before the next barrier drain.
template <int MODE>
__global__ __launch_bounds__(512, 4)
void scan_kernel(const float* __restrict__ emb, const int* __restrict__ idx,
                 unsigned* __restrict__ best_u, unsigned* __restrict__ cnt,
                 int climit) {
  __shared__ unsigned short Bb[2][128 * 64];   // 2 x 16 KB
  __shared__ int sidx[512];

  const int tid = threadIdx.x, lane = tid & 63, wv = tid >> 6;
  const int l15 = lane & 15, kq = lane >> 4;
  const int bj = blockIdx.x, stride = gridDim.x, rh = blockIdx.y;
  const int m0 = wv * 64;                      // wave's 64 rows (block-local)
  const int rbase = rh * 512;

  {
    int row = idx[rbase + tid] - 1;
    if (row < 0) row += N_ITEMS;               // numpy negative-index wrap
    sidx[tid] = row;
  }
  const int sr = tid >> 2, sg = tid & 3;       // staging: row sr, quarter sg
  __syncthreads();

  // A fragments (hi bf16) for this wave's 64 rows
  bf16x8 ah[4][2];
#pragma unroll
  for (int am = 0; am < 4; ++am) {
    const float* src = emb + (size_t)sidx[m0 + am * 16 + l15] * EMBED + kq * 8;
    cvt_hi(*(const f32x4*)(src),      *(const f32x4*)(src + 4),  ah[am][0]);
    cvt_hi(*(const f32x4*)(src + 32), *(const f32x4*)(src + 36), ah[am][1]);
  }
  const int sw = sidx[m0 + lane];              // for wave-level self-chunk test

  float bs[16];
#pragma unroll
  for (int am = 0; am < 4; ++am)
#pragma unroll
    for (int r = 0; r < 4; ++r) {
      if (MODE == 1) {
        unsigned tu = best_u[rbase + m0 + am * 16 + kq * 4 + r];
        union { unsigned u; float f; } cv;
        cv.u = (tu & 0x80000000u) ? (tu & 0x7FFFFFFFu) : ~tu;
        bs[am * 4 + r] = cv.f;
      } else {
        bs[am * 4 + r] = -3.4e38f;
      }
    }

  // prologue: load this block's first chunk (coalesced 64 B/thread)
  f32x4 raw[4];
  {
    int jr = bj * 128 + sr;
    if (jr >= N_ITEMS) jr = N_ITEMS - 1;
    const float* s = emb + (size_t)jr * EMBED + sg * 16;
#pragma unroll
    for (int i = 0; i < 4; ++i) raw[i] = *(const f32x4*)(s + 4 * i);
  }

  int p = 0;
  for (int c = bj; c < climit; c += stride) {
    // stage chunk c into LDS buffer p (granule-XOR swizzle)
    {
      bf16x8 H0, H1;
      cvt_hi(raw[0], raw[1], H0);
      cvt_hi(raw[2], raw[3], H1);
      const int g0 = (2 * sg) ^ (sr & 7), g1 = (2 * sg + 1) ^ (sr & 7);
      *(bf16x8*)(Bb[p] + sr * 64 + g0 * 8) = H0;
      *(bf16x8*)(Bb[p] + sr * 64 + g1 * 8) = H1;
    }
    __syncthreads();   // cheap drain: no global loads outstanding here

    // prefetch chunk c+stride now -> whole compute phase to complete
    {
      int nc = c + stride;
      if (nc < climit) {
        int jr = nc * 128 + sr;
        if (jr >= N_ITEMS) jr = N_ITEMS - 1;
        const float* s = emb + (size_t)jr * EMBED + sg * 16;
#pragma unroll
        for (int i = 0; i < 4; ++i) raw[i] = *(const f32x4*)(s + 4 * i);
      }
    }

    const bool masked = __any((sw >> 7) == c) | ((c + 1) * 128 > N_ITEMS);

#pragma unroll
    for (int bn = 0; bn < 8; ++bn) {
      const int row16 = bn * 16 + l15;
      const int fro = row16 * 64;
      bf16x8 bh0 = *(const bf16x8*)(Bb[p] + fro + ((kq ^ (row16 & 7)) << 3));
      bf16x8 bh1 = *(const bf16x8*)(Bb[p] + fro + (((4 | kq) ^ (row16 & 7)) << 3));
      const f32x4 zero = {0.f, 0.f, 0.f, 0.f};
      f32x4 acc[4];
#pragma unroll
      for (int am = 0; am < 4; ++am) {
        acc[am] = __builtin_amdgcn_mfma_f32_16x16x32_bf16(ah[am][0], bh0, zero, 0, 0, 0);
        acc[am] = __builtin_amdgcn_mfma_f32_16x16x32_bf16(ah[am][1], bh1, acc[am], 0, 0, 0);
      }
      const int jc = c * 128 + bn * 16 + l15;

      if (!masked) {
        if (MODE == 1) {
          bool hit = false;
#pragma unroll
          for (int sl = 0; sl < 16; ++sl)
            hit |= (acc[sl >> 2][sl & 3] >= bs[sl] - MARGIN);
          if (__any(hit)) {   // rare (~6% of bn-iters): record candidates
#pragma unroll
            for (int sl = 0; sl < 16; ++sl)
              if (acc[sl >> 2][sl & 3] >= bs[sl] - MARGIN) {
                const int gr = rbase + m0 + (sl >> 2) * 16 + kq * 4 + (sl & 3);
                unsigned pos = atomicAdd(cnt + gr, 1u);
                if (pos < CAP) g_cand[gr * CAP + pos] = (unsigned)jc;
              }
          }
        }
#pragma unroll
        for (int sl = 0; sl < 16; ++sl)
          bs[sl] = fmaxf(bs[sl], acc[sl >> 2][sl & 3]);
      } else {   // rare: chunk holds a self row or the ragged tail
#pragma unroll
        for (int sl = 0; sl < 16; ++sl) {
          const int self = sidx[m0 + (sl >> 2) * 16 + kq * 4 + (sl & 3)];
          const bool valid = (jc < N_ITEMS) && (jc != self);
          float v = valid ? acc[sl >> 2][sl & 3] : -3.4e38f;
          if (MODE == 1 && v >= bs[sl] - MARGIN) {
            const int gr = rbase + m0 + (sl >> 2) * 16 + kq * 4 + (sl & 3);
            unsigned pos = atomicAdd(cnt + gr, 1u);
            if (pos < CAP) g_cand[gr * CAP + pos] = (unsigned)jc;
          }
          bs[sl] = fmaxf(bs[sl], v);
        }
      }
    }
    p ^= 1;
  }

  if (MODE == 0) {   // publish per-row seed max
#pragma unroll
    for (int off = 1; off < 16; off <<= 1)
#pragma unroll
      for (int sl = 0; sl < 16; ++sl)
        bs[sl] = fmaxf(bs[sl], __shfl_xor(bs[sl], off, 64));
    if (l15 == 0) {
#pragma unroll
      for (int sl = 0; sl < 16; ++sl) {
        union { float f; int i; unsigned u; } cv; cv.f = bs[sl];
        unsigned mu = (cv.i < 0) ? ~cv.u : (cv.u | 0x80000000u);
        atomicMax(best_u + rbase + m0 + (sl >> 2) * 16 + kq * 4 + (sl & 3), mu);
      }
    }
  }
}

// Exact fp32 rescore: one wave per row, lanes stride the candidate list.
__global__ __launch_bounds__(512)
void rescore_kernel(const float* __restrict__ emb, const int* __restrict__ idx,
                    const unsigned* __restrict__ cnt,
                    const float* __restrict__ mn, const float* __restrict__ mx,
                    float* __restrict__ out) {
  const int lane = threadIdx.x & 63, wv = threadIdx.x >> 6;
  const int row = blockIdx.x * 8 + wv;
  int self = idx[row] - 1;
  if (self < 0) self += N_ITEMS;
  const float* a = emb + (size_t)self * EMBED;
  float av[EMBED];
#pragma unroll
  for (int k = 0; k < EMBED; k += 4) *(f32x4*)(av + k) = *(const f32x4*)(a + k);

  unsigned n = cnt[row];
  if (n > CAP) n = CAP;
  float bv = -3.4e38f;
  unsigned bj = 0xFFFFFFFFu;
  for (unsigned i = lane; i < n; i += 64) {
    unsigned j = g_cand[row * CAP + i];
    if ((int)j == self) continue;
    const float* b = emb + (size_t)j * EMBED;
    float d = 0.f;
#pragma unroll
    for (int k = 0; k < EMBED; ++k) d = fmaf(av[k], b[k], d);
    if (d > bv || (d == bv && j < bj)) { bv = d; bj = j; }
  }
#pragma unroll
  for (int off = 1; off < 64; off <<= 1) {
    float ov = __shfl_xor(bv, off, 64);
    unsigned oj = (unsigned)__shfl_xor((int)bj, off, 64);
    if (ov > bv || (ov == bv && oj < bj)) { bv = ov; bj = oj; }
  }
  if (lane == 0) {
    float lo = mn[0], hi = mx[0];
    out[row] = (float)(bj + 1);                  // indices = argmax + 1
    out[BATCH + row] = (bv - lo) / (hi - lo);    // normalized score
  }
}

extern "C" void kernel_launch(void* const* d_in, const int* in_sizes, int n_in,
                              void* d_out, int out_size, void* d_ws, size_t ws_size,
                              hipStream_t stream) {
  const float* emb = (const float*)d_in[0];
  const int* idx   = (const int*)d_in[1];
  const float* mn  = (const float*)d_in[2];
  const float* mx  = (const float*)d_in[3];
  unsigned* best_u = (unsigned*)d_ws;        // [BATCH]
  unsigned* cnt    = best_u + BATCH;         // [BATCH]

  hipMemsetAsync(d_ws, 0, 2 * BATCH * sizeof(unsigned), stream);

  // seed: items 0..16383 (128 chunks), 64 j-blocks x 2 row-halves
  scan_kernel<0><<<dim3(64, 2), dim3(512), 0, stream>>>(emb, idx, best_u, cnt,
                                                        SEED_CH);
  // fused scan: all chunks, push candidates vs (running max - margin)
  scan_kernel<1><<<dim3(256, 2), dim3(512), 0, stream>>>(emb, idx, best_u, cnt,
                                                         NCH);
  rescore_kernel<<<dim3(BATCH / 8), dim3(512), 0, stream>>>(emb, idx, cnt, mn,
                                                            mx, (float*)d_out);
}

// Round 7
// 261.959 us; speedup vs baseline: 2.5465x; 1.2581x over previous
//
#include <hip/hip_runtime.h>

#define N_ITEMS 500000
#define EMBED 64
#define BATCH 1024
#define NCH ((N_ITEMS + 127) / 128)   // 3907 chunks of 128 items
#define SEED_CH 512                   // seed region: items 0..65535
#define CAP 4096
#define MARGIN 0.75f                  // >> 2x max 1-term bf16 approx error

typedef __attribute__((ext_vector_type(8))) __bf16 bf16x8;
typedef __attribute__((ext_vector_type(4))) float f32x4;

__device__ unsigned g_cand[BATCH * CAP];   // 16 MB candidate lists

__device__ __forceinline__ void cvt_hi(const f32x4 r0, const f32x4 r1, bf16x8& H) {
#pragma unroll
  for (int k = 0; k < 4; ++k) { H[k] = (__bf16)r0[k]; H[4 + k] = (__bf16)r1[k]; }
}

__device__ __forceinline__ float u2f(unsigned tu) {
  union { unsigned u; float f; } cv;
  cv.u = (tu & 0x80000000u) ? (tu & 0x7FFFFFFFu) : ~tu;
  return cv.f;
}

// MODE 0 (seed): per-row running max over [0, climit) chunks -> atomicMax(best_u).
// MODE 1 (collect): FIXED per-slot thresholds T = seedmax - MARGIN; hot path is
// a max3-tree + ONE compare per 1024-score tile; rare slow path pushes candidates.
template <int MODE>
__global__ __launch_bounds__(512, 4)
void scan_kernel(const float* __restrict__ emb, const int* __restrict__ idx,
                 unsigned* __restrict__ best_u, unsigned* __restrict__ cnt,
                 int climit, int stride) {
  __shared__ unsigned short Bb[2][128 * 64];   // 2 x 16 KB, granule-XOR swizzled
  __shared__ int sidx[512];

  const int tid = threadIdx.x, lane = tid & 63, wv = tid >> 6;
  const int l15 = lane & 15, kq = lane >> 4;
  const int bj = blockIdx.x, rh = blockIdx.y;
  const int m0 = wv * 64, rbase = rh * 512;

  {
    int row = idx[rbase + tid] - 1;
    if (row < 0) row += N_ITEMS;               // numpy negative-index wrap
    sidx[tid] = row;
  }
  const int sr = tid >> 2, sg = tid & 3;
  __syncthreads();

  bf16x8 ah[4][2];
#pragma unroll
  for (int am = 0; am < 4; ++am) {
    const float* src = emb + (size_t)sidx[m0 + am * 16 + l15] * EMBED + kq * 8;
    cvt_hi(*(const f32x4*)(src),      *(const f32x4*)(src + 4),  ah[am][0]);
    cvt_hi(*(const f32x4*)(src + 32), *(const f32x4*)(src + 36), ah[am][1]);
  }
  const int sw = sidx[m0 + lane];

  float bs[16];       // MODE0: running max; MODE1: fixed per-slot threshold
  float Tm = 0.f;     // MODE1: min over the lane's 16 thresholds
#pragma unroll
  for (int am = 0; am < 4; ++am)
#pragma unroll
    for (int r = 0; r < 4; ++r) {
      const int sl = am * 4 + r;
      if (MODE == 0) {
        bs[sl] = -3.4e38f;
      } else {
        bs[sl] = u2f(best_u[rbase + m0 + am * 16 + kq * 4 + r]) - MARGIN;
      }
    }
  if (MODE == 1) {
    Tm = bs[0];
#pragma unroll
    for (int sl = 1; sl < 16; ++sl) Tm = fminf(Tm, bs[sl]);
  }

  // prologue: load this block's first chunk (coalesced 64 B/thread)
  f32x4 raw[4];
  {
    int jr = bj * 128 + sr;
    if (jr >= N_ITEMS) jr = N_ITEMS - 1;
    const float* s = emb + (size_t)jr * EMBED + sg * 16;
#pragma unroll
    for (int i = 0; i < 4; ++i) raw[i] = *(const f32x4*)(s + 4 * i);
  }

  int p = 0;
  for (int c = bj; c < climit; c += stride) {
    {  // stage chunk c
      bf16x8 H0, H1;
      cvt_hi(raw[0], raw[1], H0);
      cvt_hi(raw[2], raw[3], H1);
      const int g0 = (2 * sg) ^ (sr & 7), g1 = (2 * sg + 1) ^ (sr & 7);
      *(bf16x8*)(Bb[p] + sr * 64 + g0 * 8) = H0;
      *(bf16x8*)(Bb[p] + sr * 64 + g1 * 8) = H1;
    }
    __syncthreads();
    {  // prefetch chunk c+stride: whole compute phase to complete
      int nc = c + stride;
      if (nc < climit) {
        int jr = nc * 128 + sr;
        if (jr >= N_ITEMS) jr = N_ITEMS - 1;
        const float* s = emb + (size_t)jr * EMBED + sg * 16;
#pragma unroll
        for (int i = 0; i < 4; ++i) raw[i] = *(const f32x4*)(s + 4 * i);
      }
    }

    const bool masked = (MODE == 0) && __any((sw >> 7) == c);

#pragma unroll
    for (int bn = 0; bn < 8; ++bn) {
      const int row16 = bn * 16 + l15;
      const int fro = row16 * 64;
      bf16x8 bh0 = *(const bf16x8*)(Bb[p] + fro + ((kq ^ (row16 & 7)) << 3));
      bf16x8 bh1 = *(const bf16x8*)(Bb[p] + fro + (((4 | kq) ^ (row16 & 7)) << 3));
      const f32x4 zero = {0.f, 0.f, 0.f, 0.f};
      f32x4 acc[4];
#pragma unroll
      for (int am = 0; am < 4; ++am) {
        acc[am] = __builtin_amdgcn_mfma_f32_16x16x32_bf16(ah[am][0], bh0, zero, 0, 0, 0);
        acc[am] = __builtin_amdgcn_mfma_f32_16x16x32_bf16(ah[am][1], bh1, acc[am], 0, 0, 0);
      }

      if (MODE == 0) {
        if (!masked) {
#pragma unroll
          for (int sl = 0; sl < 16; ++sl)
            bs[sl] = fmaxf(bs[sl], acc[sl >> 2][sl & 3]);
        } else {   // rare: chunk holds a self row
          const int jc = c * 128 + bn * 16 + l15;
#pragma unroll
          for (int sl = 0; sl < 16; ++sl) {
            const int self = sidx[m0 + (sl >> 2) * 16 + kq * 4 + (sl & 3)];
            float v = (jc != self) ? acc[sl >> 2][sl & 3] : -3.4e38f;
            bs[sl] = fmaxf(bs[sl], v);
          }
        }
      } else {
        // hot path: tree-max of the 16 scores, one compare vs Tm
        float gm = fmaxf(acc[0][0], acc[0][1]);
#pragma unroll
        for (int sl = 2; sl < 16; ++sl) gm = fmaxf(gm, acc[sl >> 2][sl & 3]);
        if (__any(gm >= Tm)) {   // rare (~3-5% of tiles): per-slot push check
          const int jc = c * 128 + bn * 16 + l15;
#pragma unroll
          for (int sl = 0; sl < 16; ++sl) {
            if (acc[sl >> 2][sl & 3] >= bs[sl] && jc < N_ITEMS) {
              const int gr = rbase + m0 + (sl >> 2) * 16 + kq * 4 + (sl & 3);
              unsigned pos = atomicAdd(cnt + gr, 1u);
              if (pos < CAP) g_cand[gr * CAP + pos] = (unsigned)jc;
            }
          }
        }
      }
    }
    p ^= 1;
  }

  if (MODE == 0) {   // publish per-row seed max (self excluded)
#pragma unroll
    for (int off = 1; off < 16; off <<= 1)
#pragma unroll
      for (int sl = 0; sl < 16; ++sl)
        bs[sl] = fmaxf(bs[sl], __shfl_xor(bs[sl], off, 64));
    if (l15 == 0) {
#pragma unroll
      for (int sl = 0; sl < 16; ++sl) {
        union { float f; int i; unsigned u; } cv; cv.f = bs[sl];
        unsigned mu = (cv.i < 0) ? ~cv.u : (cv.u | 0x80000000u);
        atomicMax(best_u + rbase + m0 + (sl >> 2) * 16 + kq * 4 + (sl & 3), mu);
      }
    }
  }
}

// Exact fp32 rescore (one wave per row); flags rows whose list overflowed.
__global__ __launch_bounds__(512)
void rescore_kernel(const float* __restrict__ emb, const int* __restrict__ idx,
                    const unsigned* __restrict__ cnt,
                    const float* __restrict__ mn, const float* __restrict__ mx,
                    float* __restrict__ out, unsigned* __restrict__ ov_cnt,
                    unsigned* __restrict__ ov_rows) {
  const int lane = threadIdx.x & 63, wv = threadIdx.x >> 6;
  const int row = blockIdx.x * 8 + wv;
  int self = idx[row] - 1;
  if (self < 0) self += N_ITEMS;
  const float* a = emb + (size_t)self * EMBED;
  float av[EMBED];
#pragma unroll
  for (int k = 0; k < EMBED; k += 4) *(f32x4*)(av + k) = *(const f32x4*)(a + k);

  unsigned n = cnt[row];
  if (n > CAP) {
    if (lane == 0) {                      // exact cleanup will overwrite this row
      unsigned pos = atomicAdd(ov_cnt, 1u);
      ov_rows[pos] = (unsigned)row;
    }
    n = CAP;
  }
  float bv = -3.4e38f;
  unsigned bj = 0xFFFFFFFFu;
  for (unsigned i = lane; i < n; i += 64) {
    unsigned j = g_cand[row * CAP + i];
    if ((int)j == self) continue;
    const float* b = emb + (size_t)j * EMBED;
    float d = 0.f;
#pragma unroll
    for (int k = 0; k < EMBED; ++k) d = fmaf(av[k], b[k], d);
    if (d > bv || (d == bv && j < bj)) { bv = d; bj = j; }
  }
#pragma unroll
  for (int off = 1; off < 64; off <<= 1) {
    float ov = __shfl_xor(bv, off, 64);
    unsigned oj = (unsigned)__shfl_xor((int)bj, off, 64);
    if (ov > bv || (ov == bv && oj < bj)) { bv = ov; bj = oj; }
  }
  if (lane == 0) {
    float lo = mn[0], hi = mx[0];
    out[row] = (float)(bj + 1);
    out[BATCH + row] = (bv - lo) / (hi - lo);
  }
}

// Exact brute-force for overflowed rows (rare; E is L3-resident by now).
__global__ __launch_bounds__(256)
void cleanup_scan(const float* __restrict__ emb, const int* __restrict__ idx,
                  const unsigned* __restrict__ ov_cnt,
                  const unsigned* __restrict__ ov_rows,
                  unsigned long long* __restrict__ best64) {
  unsigned nov = *ov_cnt;
  if (nov == 0) return;
  if (nov > BATCH) nov = BATCH;
  __shared__ float av[EMBED];
  const int tid = threadIdx.x, lane = tid & 63;
  for (unsigned oi = 0; oi < nov; ++oi) {
    const int row = (int)ov_rows[oi];
    int self = idx[row] - 1;
    if (self < 0) self += N_ITEMS;
    __syncthreads();
    if (tid < EMBED) av[tid] = emb[(size_t)self * EMBED + tid];
    __syncthreads();
    const int j = blockIdx.x * 256 + tid;
    unsigned long long key = 0ull;
    if (j < N_ITEMS && j != self) {
      const float* b = emb + (size_t)j * EMBED;
      float d = 0.f;
#pragma unroll
      for (int k = 0; k < EMBED; ++k) d = fmaf(av[k], b[k], d);
      union { float f; int i; unsigned u; } cv; cv.f = d;
      unsigned mu = (cv.i < 0) ? ~cv.u : (cv.u | 0x80000000u);
      key = ((unsigned long long)mu << 32) |
            (unsigned long long)(0xFFFFFFFFu - (unsigned)j);
    }
#pragma unroll
    for (int off = 1; off < 64; off <<= 1) {
      unsigned long long ok = __shfl_xor(key, off, 64);
      if (ok > key) key = ok;
    }
    if (lane == 0) atomicMax(best64 + row, key);
  }
}

__global__ void cleanup_write(const unsigned* __restrict__ cnt,
                              const unsigned long long* __restrict__ best64,
                              const float* __restrict__ mn,
                              const float* __restrict__ mx,
                              float* __restrict__ out) {
  int r = blockIdx.x * blockDim.x + threadIdx.x;
  if (r >= BATCH) return;
  if (cnt[r] <= CAP) return;
  unsigned long long k = best64[r];
  unsigned mu = (unsigned)(k >> 32);
  unsigned j  = 0xFFFFFFFFu - (unsigned)(k & 0xFFFFFFFFull);
  union { unsigned u; float f; } cv;
  cv.u = (mu & 0x80000000u) ? (mu & 0x7FFFFFFFu) : ~mu;
  float lo = mn[0], hi = mx[0];
  out[r] = (float)(j + 1);
  out[BATCH + r] = (cv.f - lo) / (hi - lo);
}

extern "C" void kernel_launch(void* const* d_in, const int* in_sizes, int n_in,
                              void* d_out, int out_size, void* d_ws, size_t ws_size,
                              hipStream_t stream) {
  const float* emb = (const float*)d_in[0];
  const int* idx   = (const int*)d_in[1];
  const float* mn  = (const float*)d_in[2];
  const float* mx  = (const float*)d_in[3];
  unsigned* ws     = (unsigned*)d_ws;
  unsigned* best_u = ws;                   // [1024]
  unsigned* cnt    = ws + 1024;            // [1024]
  unsigned* ov_cnt = ws + 2048;            // [1] (+3 pad)
  unsigned* ov_rows= ws + 2052;            // [1024]
  unsigned long long* best64 = (unsigned long long*)(ws + 3076);  // [1024], 8B-aligned

  hipMemsetAsync(d_ws, 0, 3076 * 4 + 1024 * 8, stream);

  // seed: per-row approx max over items 0..65535
  scan_kernel<0><<<dim3(128, 2), dim3(512), 0, stream>>>(emb, idx, best_u, cnt,
                                                         SEED_CH, 128);
  // collect: full scan, push everything >= seedmax - margin
  scan_kernel<1><<<dim3(256, 2), dim3(512), 0, stream>>>(emb, idx, best_u, cnt,
                                                         NCH, 256);
  rescore_kernel<<<dim3(BATCH / 8), dim3(512), 0, stream>>>(
      emb, idx, cnt, mn, mx, (float*)d_out, ov_cnt, ov_rows);
  cleanup_scan<<<dim3(2048), dim3(256), 0, stream>>>(emb, idx, ov_cnt, ov_rows,
                                                     best64);
  cleanup_write<<<dim3(4), dim3(256), 0, stream>>>(cnt, best64, mn, mx,
                                                   (float*)d_out);
}